// Round 3
// baseline (6335.855 us; speedup 1.0000x reference)
//
#include <hip/hip_runtime.h>
#include <cstdint>
#include <cstddef>

typedef unsigned short u16;
typedef __bf16 bf16x8 __attribute__((ext_vector_type(8)));
typedef float f32x4 __attribute__((ext_vector_type(4)));
typedef unsigned short u16x8 __attribute__((ext_vector_type(8)));
typedef unsigned short u16x4 __attribute__((ext_vector_type(4)));

static constexpr int D = 1024, FF = 4096, L = 6, H = 16, SEQ = 1024, BATCH = 8;
static constexpr int NTOK = BATCH * SEQ; // 8192

__device__ __forceinline__ float b2f(u16 u){ unsigned int i = ((unsigned int)u) << 16; return __builtin_bit_cast(float, i); }
__device__ __forceinline__ u16 f2b(float f){
  unsigned int i = __builtin_bit_cast(unsigned int, f);
  i += 0x7FFFu + ((i >> 16) & 1u);           // round-to-nearest-even
  return (u16)(i >> 16);
}

// ---------------- embedding + positional encoding ----------------
// x[n][d] = emb[tok[n]][d]*32 + pe(n%1024, d);  writes fp32 x and bf16 xb
__global__ __launch_bounds__(256) void embed_k(const int* __restrict__ tok,
    const float* __restrict__ emb, float* __restrict__ x, u16* __restrict__ xb)
{
  int idx = blockIdx.x * 256 + threadIdx.x;   // one thread per 4 elements
  int row = idx >> 8;                          // 256 groups per row
  int g = idx & 255;
  int t = tok[row];
  int s = row & (SEQ - 1);
  int d0 = g * 4;
  const float c = -logf(10000.0f) / (float)D;
  float a0 = (float)s * expf((float)d0 * c);
  float a1 = (float)s * expf((float)(d0 + 2) * c);
  float4 e = *(const float4*)&emb[(size_t)t * D + d0];
  float v0 = e.x * 32.0f + sinf(a0);
  float v1 = e.y * 32.0f + cosf(a0);
  float v2 = e.z * 32.0f + sinf(a1);
  float v3 = e.w * 32.0f + cosf(a1);
  size_t o = (size_t)row * D + d0;
  *(float4*)&x[o] = make_float4(v0, v1, v2, v3);
  u16x4 bb = { f2b(v0), f2b(v1), f2b(v2), f2b(v3) };
  *(u16x4*)&xb[o] = bb;
}

// ---------------- fused residual + LayerNorm ----------------
// y = LN(xin + delta_bf16); writes fp32 xout (optional) and bf16 bout (optional)
__global__ __launch_bounds__(256) void ln_k(const float* __restrict__ xin,
    const u16* __restrict__ delta, const float* __restrict__ w, const float* __restrict__ bi,
    float* __restrict__ xout, u16* __restrict__ bout, float eps)
{
  int row = blockIdx.x, tid = threadIdx.x;
  int wave = tid >> 6, lane = tid & 63;
  size_t base = (size_t)row * D;
  int c0 = tid * 4;
  float4 v = *(const float4*)&xin[base + c0];
  if (delta){
    u16x4 dd = *(const u16x4*)&delta[base + c0];
    v.x += b2f(dd[0]); v.y += b2f(dd[1]); v.z += b2f(dd[2]); v.w += b2f(dd[3]);
  }
  float s = v.x + v.y + v.z + v.w;
  #pragma unroll
  for (int o = 32; o >= 1; o >>= 1) s += __shfl_down(s, o, 64);
  __shared__ float red[4];
  if (lane == 0) red[wave] = s;
  __syncthreads();
  float mean = (red[0] + red[1] + red[2] + red[3]) * (1.0f / D);
  __syncthreads();
  float d0 = v.x - mean, d1 = v.y - mean, d2 = v.z - mean, d3 = v.w - mean;
  float s2 = d0*d0 + d1*d1 + d2*d2 + d3*d3;
  #pragma unroll
  for (int o = 32; o >= 1; o >>= 1) s2 += __shfl_down(s2, o, 64);
  if (lane == 0) red[wave] = s2;
  __syncthreads();
  float var = (red[0] + red[1] + red[2] + red[3]) * (1.0f / D);
  float inv = rsqrtf(var + eps);
  float4 wv = *(const float4*)&w[c0];
  float4 bv = *(const float4*)&bi[c0];
  float o0 = d0 * inv * wv.x + bv.x;
  float o1 = d1 * inv * wv.y + bv.y;
  float o2 = d2 * inv * wv.z + bv.z;
  float o3 = d3 * inv * wv.w + bv.w;
  if (xout) *(float4*)&xout[base + c0] = make_float4(o0, o1, o2, o3);
  if (bout){
    u16x4 ob = { f2b(o0), f2b(o1), f2b(o2), f2b(o3) };
    *(u16x4*)&bout[base + c0] = ob;
  }
}

// ---------------- fp32 -> bf16 transpose (weights -> B^T form) ----------------
// in: R x C row-major fp32, out: C x R row-major bf16
__global__ __launch_bounds__(256) void transpose_k(const float* __restrict__ in,
    u16* __restrict__ out, int R, int C)
{
  __shared__ __align__(16) u16 t[32][33];
  int bx = blockIdx.x, by = blockIdx.y;
  int x = threadIdx.x & 31, y = threadIdx.x >> 5;  // y: 0..7
  #pragma unroll
  for (int r = 0; r < 4; r++){
    int row = by * 32 + y + r * 8;
    t[y + r * 8][x] = f2b(in[(size_t)row * C + bx * 32 + x]);
  }
  __syncthreads();
  #pragma unroll
  for (int r = 0; r < 4; r++){
    int orow = bx * 32 + y + r * 8;
    out[(size_t)orow * R + by * 32 + x] = t[x][y + r * 8];
  }
}

// ---------------- bf16 MFMA GEMM, C = A @ B with B^T input ----------------
// A: [M][K] bf16, Bt: [N][K] bf16. 128x128 tile, BK=32, 4 waves (2x2 of 64x64).
// EPI: 0 = plain bf16 out, 1 = bias+relu bf16 out, 2 = bias bf16 out
template<int EPI>
__global__ __launch_bounds__(256) void gemm_bt(const u16* __restrict__ A,
    const u16* __restrict__ Bt, u16* __restrict__ C, const float* __restrict__ bias,
    int M, int N, int K)
{
  __shared__ __align__(16) u16 lA[4096];  // [128 rows][32 k]
  __shared__ __align__(16) u16 lB[4096];
  const int tid = threadIdx.x;
  const int wave = tid >> 6, lane = tid & 63;
  const int quad = lane >> 4, l16 = lane & 15;
  const int m0 = blockIdx.y * 128, n0 = blockIdx.x * 128;
  const int wm = (wave >> 1) * 64, wn = (wave & 1) * 64;
  const int sr = tid >> 2;          // staging row 0..63
  const int sc = (tid & 3) * 8;     // staging col {0,8,16,24}
  const u16* pa = A  + (size_t)(m0 + sr) * K + sc;
  const u16* pb = Bt + (size_t)(n0 + sr) * K + sc;
  const size_t rstep = (size_t)64 * K;
  f32x4 acc[4][4] = {};

  for (int kt = 0; kt < K; kt += 32){
    u16x8 a0 = *(const u16x8*)(pa + kt);
    u16x8 a1 = *(const u16x8*)(pa + rstep + kt);
    u16x8 b0 = *(const u16x8*)(pb + kt);
    u16x8 b1 = *(const u16x8*)(pb + rstep + kt);
    __syncthreads();                 // previous iteration's LDS reads complete
    *(u16x8*)&lA[sr * 32 + sc]        = a0;
    *(u16x8*)&lA[(sr + 64) * 32 + sc] = a1;
    *(u16x8*)&lB[sr * 32 + sc]        = b0;
    *(u16x8*)&lB[(sr + 64) * 32 + sc] = b1;
    __syncthreads();                 // tile visible
    bf16x8 af[4], bfv[4];
    #pragma unroll
    for (int i = 0; i < 4; i++){
      af[i]  = __builtin_bit_cast(bf16x8, *(const u16x8*)&lA[(wm + i*16 + l16)*32 + quad*8]);
      bfv[i] = __builtin_bit_cast(bf16x8, *(const u16x8*)&lB[(wn + i*16 + l16)*32 + quad*8]);
    }
    #pragma unroll
    for (int i = 0; i < 4; i++)
      #pragma unroll
      for (int j = 0; j < 4; j++)
        acc[i][j] = __builtin_amdgcn_mfma_f32_16x16x32_bf16(af[i], bfv[j], acc[i][j], 0, 0, 0);
  }
  // C/D layout: col = lane&15, row = quad*4 + reg
  #pragma unroll
  for (int i = 0; i < 4; i++){
    const int gr = m0 + wm + i*16 + quad*4;
    #pragma unroll
    for (int j = 0; j < 4; j++){
      const int gc = n0 + wn + j*16 + l16;
      float bv = 0.0f;
      if constexpr (EPI >= 1) bv = bias[gc];
      #pragma unroll
      for (int r = 0; r < 4; r++){
        float v = acc[i][j][r] + bv;
        if constexpr (EPI == 1) v = fmaxf(v, 0.0f);
        C[(size_t)(gr + r) * N + gc] = f2b(v);
      }
    }
  }
}

// ---------------- flash attention (VALU, online softmax) ----------------
// qkv: [NTOK][3*D] bf16 (q|k|v), ctx out: [NTOK][D] bf16
__global__ __launch_bounds__(256) void attn_k(const u16* __restrict__ qkv,
    const int* __restrict__ tok, u16* __restrict__ ctx)
{
  __shared__ __align__(16) float Qs[64][68];
  __shared__ __align__(16) float Ks[64][68];   // reused as score/P tile
  __shared__ __align__(16) float Vt[64][68];   // V transposed: Vt[dk][k]
  __shared__ float mrow[64], lrow[64], arow[64], maskv[64];
  const int tid = threadIdx.x;
  const int qt = blockIdx.x, bh = blockIdx.y;
  const int b = bh >> 4, h = bh & (H - 1);
  const int q0 = qt * 64;
  const int tq = tid & 15, tk = tid >> 4;
  const int sr = tid >> 3;             // staging row 0..31
  const int scc = (tid & 7) * 8;       // staging col
  #pragma unroll
  for (int r2 = 0; r2 < 2; r2++){
    int r = sr + r2 * 32;
    u16x8 u = *(const u16x8*)&qkv[((size_t)(b*SEQ + q0 + r)) * 3072 + h*64 + scc];
    #pragma unroll
    for (int c2 = 0; c2 < 8; c2++) Qs[r][scc + c2] = b2f(u[c2]) * 0.125f;
  }
  if (tid < 64){ mrow[tid] = -1.0e30f; lrow[tid] = 0.0f; }
  float O[4][4] = {};
  __syncthreads();
  for (int kt = 0; kt < 16; ++kt){
    const int k0 = kt * 64;
    #pragma unroll
    for (int r2 = 0; r2 < 2; r2++){
      int r = sr + r2 * 32;
      size_t rb = ((size_t)(b*SEQ + k0 + r)) * 3072 + h*64 + scc;
      u16x8 uk = *(const u16x8*)&qkv[rb + 1024];
      u16x8 uv = *(const u16x8*)&qkv[rb + 2048];
      #pragma unroll
      for (int c2 = 0; c2 < 8; c2++){
        Ks[r][scc + c2] = b2f(uk[c2]);
        Vt[scc + c2][r] = b2f(uv[c2]);
      }
    }
    if (tid < 64) maskv[tid] = (tok[b*SEQ + k0 + tid] != 0) ? 0.0f : -1.0e9f;
    __syncthreads();
    float sc4[4][4] = {};
    for (int j4 = 0; j4 < 64; j4 += 4){
      float4 qv[4], kv[4];
      #pragma unroll
      for (int i = 0; i < 4; i++) qv[i] = *(const float4*)&Qs[tq + 16*i][j4];
      #pragma unroll
      for (int j = 0; j < 4; j++) kv[j] = *(const float4*)&Ks[tk + 16*j][j4];
      #pragma unroll
      for (int i = 0; i < 4; i++)
        #pragma unroll
        for (int j = 0; j < 4; j++)
          sc4[i][j] += qv[i].x*kv[j].x + qv[i].y*kv[j].y + qv[i].z*kv[j].z + qv[i].w*kv[j].w;
    }
    __syncthreads();                    // all K reads done before overwrite
    #pragma unroll
    for (int i = 0; i < 4; i++)
      #pragma unroll
      for (int j = 0; j < 4; j++)
        Ks[tq + 16*i][tk + 16*j] = sc4[i][j] + maskv[tk + 16*j];
    __syncthreads();
    { // online softmax row update: 4 threads per row
      int r = tid >> 2, p = tid & 3;
      float mx = -1.0e30f;
      #pragma unroll
      for (int k2 = 0; k2 < 16; k2++) mx = fmaxf(mx, Ks[r][p*16 + k2]);
      mx = fmaxf(mx, __shfl_xor(mx, 1, 64));
      mx = fmaxf(mx, __shfl_xor(mx, 2, 64));
      float mo = mrow[r];
      float mn = fmaxf(mo, mx);
      float sum = 0.0f;
      #pragma unroll
      for (int k2 = 0; k2 < 16; k2++){
        float e = __expf(Ks[r][p*16 + k2] - mn);
        Ks[r][p*16 + k2] = e;
        sum += e;
      }
      sum += __shfl_xor(sum, 1, 64);
      sum += __shfl_xor(sum, 2, 64);
      if (p == 0){
        arow[r] = __expf(mo - mn);
        lrow[r] = lrow[r] * arow[r] + sum;
        mrow[r] = mn;
      }
    }
    __syncthreads();
    #pragma unroll
    for (int i = 0; i < 4; i++){
      float al = arow[tq + 16*i];
      #pragma unroll
      for (int j = 0; j < 4; j++) O[i][j] *= al;
    }
    for (int k4 = 0; k4 < 64; k4 += 4){
      float4 pv[4], vv[4];
      #pragma unroll
      for (int i = 0; i < 4; i++) pv[i] = *(const float4*)&Ks[tq + 16*i][k4];
      #pragma unroll
      for (int j = 0; j < 4; j++) vv[j] = *(const float4*)&Vt[tk + 16*j][k4];
      #pragma unroll
      for (int i = 0; i < 4; i++)
        #pragma unroll
        for (int j = 0; j < 4; j++)
          O[i][j] += pv[i].x*vv[j].x + pv[i].y*vv[j].y + pv[i].z*vv[j].z + pv[i].w*vv[j].w;
    }
    __syncthreads();
  }
  #pragma unroll
  for (int i = 0; i < 4; i++){
    float inv = 1.0f / lrow[tq + 16*i];
    size_t ro = ((size_t)(b*SEQ + q0 + tq + 16*i)) * D + h*64;
    #pragma unroll
    for (int j = 0; j < 4; j++)
      ctx[ro + tk + 16*j] = f2b(O[i][j] * inv);
  }
}

// ---------------- host ----------------
extern "C" void kernel_launch(void* const* d_in, const int* in_sizes, int n_in,
                              void* d_out, int out_size, void* d_ws, size_t ws_size,
                              hipStream_t stream)
{
  (void)in_sizes; (void)n_in; (void)out_size; (void)ws_size;
  const int*   tok = (const int*)d_in[0];
  const float* emb = (const float*)d_in[1];
  const float* Wq  = (const float*)d_in[2];
  const float* Wk  = (const float*)d_in[3];
  const float* Wv  = (const float*)d_in[4];
  const float* Wo  = (const float*)d_in[5];
  const float* W1  = (const float*)d_in[6];
  const float* b1  = (const float*)d_in[7];
  const float* W2  = (const float*)d_in[8];
  const float* b2  = (const float*)d_in[9];
  const float* ln1w = (const float*)d_in[10];
  const float* ln1b = (const float*)d_in[11];
  const float* ln2w = (const float*)d_in[12];
  const float* ln2b = (const float*)d_in[13];
  const float* fnw  = (const float*)d_in[14];
  const float* fnb  = (const float*)d_in[15];
  float* out = (float*)d_out;

  // workspace layout (144 MB total):
  char* wp = (char*)d_ws;
  float* x  = (float*)wp;                              // fp32 residual, 32 MB
  u16* xb   = (u16*)(wp + (size_t)32*1024*1024);       // bf16 residual, 16 MB
  u16* big  = (u16*)(wp + (size_t)48*1024*1024);       // qkv (48 MB) / h1 chunk (32 MB)
  u16* ctx  = (u16*)(wp + (size_t)96*1024*1024);       // 16 MB
  u16* tmp  = (u16*)(wp + (size_t)112*1024*1024);      // bf16 delta, 16 MB
  u16* wtmp = (u16*)(wp + (size_t)128*1024*1024);      // transposed bf16 weights, 16 MB

  embed_k<<<NTOK, 256, 0, stream>>>(tok, emb, x, xb);

  for (int l = 0; l < L; ++l){
    // QKV: transpose Wq|Wk|Wv into wtmp as fused [3072][1024] bf16 B^T
    transpose_k<<<dim3(D/32, D/32), 256, 0, stream>>>(Wq + (size_t)l*D*D, wtmp, D, D);
    transpose_k<<<dim3(D/32, D/32), 256, 0, stream>>>(Wk + (size_t)l*D*D, wtmp + (size_t)D*D, D, D);
    transpose_k<<<dim3(D/32, D/32), 256, 0, stream>>>(Wv + (size_t)l*D*D, wtmp + (size_t)2*D*D, D, D);
    gemm_bt<0><<<dim3(3*D/128, NTOK/128), 256, 0, stream>>>(xb, wtmp, big, nullptr, NTOK, 3*D, D);
    attn_k<<<dim3(SEQ/64, BATCH*H), 256, 0, stream>>>(big, tok, ctx);
    // attn output projection
    transpose_k<<<dim3(D/32, D/32), 256, 0, stream>>>(Wo + (size_t)l*D*D, wtmp, D, D);
    gemm_bt<0><<<dim3(D/128, NTOK/128), 256, 0, stream>>>(ctx, wtmp, tmp, nullptr, NTOK, D, D);
    ln_k<<<NTOK, 256, 0, stream>>>(x, tmp, ln1w + (size_t)l*D, ln1b + (size_t)l*D, x, xb, 1e-6f);
    // FFN: W1^T at wtmp, W2^T at wtmp + D*FF; h1 chunked over M into `big`
    transpose_k<<<dim3(FF/32, D/32), 256, 0, stream>>>(W1 + (size_t)l*D*FF, wtmp, D, FF);
    transpose_k<<<dim3(D/32, FF/32), 256, 0, stream>>>(W2 + (size_t)l*FF*D, wtmp + (size_t)D*FF, FF, D);
    for (int mc = 0; mc < 2; ++mc){
      const u16* ain = xb + (size_t)mc*4096*D;
      u16* cout = tmp + (size_t)mc*4096*D;
      gemm_bt<1><<<dim3(FF/128, 4096/128), 256, 0, stream>>>(ain, wtmp, big, b1 + (size_t)l*FF, 4096, FF, D);
      gemm_bt<2><<<dim3(D/128, 4096/128), 256, 0, stream>>>(big, wtmp + (size_t)D*FF, cout, b2 + (size_t)l*D, 4096, D, FF);
    }
    ln_k<<<NTOK, 256, 0, stream>>>(x, tmp, ln2w + (size_t)l*D, ln2b + (size_t)l*D, x, xb, 1e-6f);
  }
  ln_k<<<NTOK, 256, 0, stream>>>(x, nullptr, fnw, fnb, out, nullptr, 1e-5f);
}

// Round 4
// 3770.185 us; speedup vs baseline: 1.6805x; 1.6805x over previous
//
#include <hip/hip_runtime.h>
#include <cstdint>
#include <cstddef>

typedef unsigned short u16;
typedef __bf16 bf16x8 __attribute__((ext_vector_type(8)));
typedef float f32x4 __attribute__((ext_vector_type(4)));
typedef unsigned short u16x8 __attribute__((ext_vector_type(8)));
typedef unsigned short u16x4 __attribute__((ext_vector_type(4)));
typedef __attribute__((address_space(1))) void* gas_ptr;
typedef __attribute__((address_space(3))) void* las_ptr;

static constexpr int D = 1024, FF = 4096, L = 6, H = 16, SEQ = 1024, BATCH = 8;
static constexpr int NTOK = BATCH * SEQ; // 8192

__device__ __forceinline__ float b2f(u16 u){ unsigned int i = ((unsigned int)u) << 16; return __builtin_bit_cast(float, i); }
__device__ __forceinline__ u16 f2b(float f){
  unsigned int i = __builtin_bit_cast(unsigned int, f);
  i += 0x7FFFu + ((i >> 16) & 1u);           // round-to-nearest-even
  return (u16)(i >> 16);
}
__device__ __forceinline__ void gload16(const void* g, void* l){
  // async global->LDS DMA, 16B/lane; LDS dest = wave-uniform base + lane*16
  __builtin_amdgcn_global_load_lds((gas_ptr)g, (las_ptr)l, 16, 0, 0);
}

// ---------------- embedding + positional encoding ----------------
__global__ __launch_bounds__(256) void embed_k(const int* __restrict__ tok,
    const float* __restrict__ emb, float* __restrict__ x, u16* __restrict__ xb)
{
  int idx = blockIdx.x * 256 + threadIdx.x;   // one thread per 4 elements
  int row = idx >> 8;
  int g = idx & 255;
  int t = tok[row];
  int s = row & (SEQ - 1);
  int d0 = g * 4;
  const float c = -logf(10000.0f) / (float)D;
  float a0 = (float)s * expf((float)d0 * c);
  float a1 = (float)s * expf((float)(d0 + 2) * c);
  float4 e = *(const float4*)&emb[(size_t)t * D + d0];
  float v0 = e.x * 32.0f + sinf(a0);
  float v1 = e.y * 32.0f + cosf(a0);
  float v2 = e.z * 32.0f + sinf(a1);
  float v3 = e.w * 32.0f + cosf(a1);
  size_t o = (size_t)row * D + d0;
  *(float4*)&x[o] = make_float4(v0, v1, v2, v3);
  u16x4 bb = { f2b(v0), f2b(v1), f2b(v2), f2b(v3) };
  *(u16x4*)&xb[o] = bb;
}

// ---------------- fused residual + LayerNorm ----------------
__global__ __launch_bounds__(256) void ln_k(const float* __restrict__ xin,
    const u16* __restrict__ delta, const float* __restrict__ w, const float* __restrict__ bi,
    float* __restrict__ xout, u16* __restrict__ bout, float eps)
{
  int row = blockIdx.x, tid = threadIdx.x;
  int wave = tid >> 6, lane = tid & 63;
  size_t base = (size_t)row * D;
  int c0 = tid * 4;
  float4 v = *(const float4*)&xin[base + c0];
  if (delta){
    u16x4 dd = *(const u16x4*)&delta[base + c0];
    v.x += b2f(dd[0]); v.y += b2f(dd[1]); v.z += b2f(dd[2]); v.w += b2f(dd[3]);
  }
  float s = v.x + v.y + v.z + v.w;
  #pragma unroll
  for (int o = 32; o >= 1; o >>= 1) s += __shfl_down(s, o, 64);
  __shared__ float red[4];
  if (lane == 0) red[wave] = s;
  __syncthreads();
  float mean = (red[0] + red[1] + red[2] + red[3]) * (1.0f / D);
  __syncthreads();
  float d0 = v.x - mean, d1 = v.y - mean, d2 = v.z - mean, d3 = v.w - mean;
  float s2 = d0*d0 + d1*d1 + d2*d2 + d3*d3;
  #pragma unroll
  for (int o = 32; o >= 1; o >>= 1) s2 += __shfl_down(s2, o, 64);
  if (lane == 0) red[wave] = s2;
  __syncthreads();
  float var = (red[0] + red[1] + red[2] + red[3]) * (1.0f / D);
  float inv = rsqrtf(var + eps);
  float4 wv = *(const float4*)&w[c0];
  float4 bv = *(const float4*)&bi[c0];
  float o0 = d0 * inv * wv.x + bv.x;
  float o1 = d1 * inv * wv.y + bv.y;
  float o2 = d2 * inv * wv.z + bv.z;
  float o3 = d3 * inv * wv.w + bv.w;
  if (xout) *(float4*)&xout[base + c0] = make_float4(o0, o1, o2, o3);
  if (bout){
    u16x4 ob = { f2b(o0), f2b(o1), f2b(o2), f2b(o3) };
    *(u16x4*)&bout[base + c0] = ob;
  }
}

// ---------------- fp32 -> bf16 transpose (weights -> B^T form) ----------------
__global__ __launch_bounds__(256) void transpose_k(const float* __restrict__ in,
    u16* __restrict__ out, int R, int C)
{
  __shared__ __align__(16) u16 t[32][33];
  int bx = blockIdx.x, by = blockIdx.y;
  int x = threadIdx.x & 31, y = threadIdx.x >> 5;
  #pragma unroll
  for (int r = 0; r < 4; r++){
    int row = by * 32 + y + r * 8;
    t[y + r * 8][x] = f2b(in[(size_t)row * C + bx * 32 + x]);
  }
  __syncthreads();
  #pragma unroll
  for (int r = 0; r < 4; r++){
    int orow = bx * 32 + y + r * 8;
    out[(size_t)orow * R + by * 32 + x] = t[x][y + r * 8];
  }
}

// ---------------- bf16 MFMA GEMM (m97 structure: global_load_lds w=16) ----------
// A: [M][K] bf16, Bt: [N][K] bf16. 128x128 tile, BK=32, 4 waves (2x2 of 64x64).
// EPI: 0 = plain bf16 out, 1 = bias+relu bf16 out, 2 = bias bf16 out
template<int EPI>
__global__ __launch_bounds__(256) void gemm_bt(const u16* __restrict__ A,
    const u16* __restrict__ Bt, u16* __restrict__ C, const float* __restrict__ bias,
    int M, int N, int K)
{
  __shared__ __align__(16) u16 lA[4096];  // [128 rows][32 k]
  __shared__ __align__(16) u16 lB[4096];
  const int tid = threadIdx.x;
  const int wave = tid >> 6, lane = tid & 63;
  const int quad = lane >> 4, l16 = lane & 15;
  const int m0 = blockIdx.y * 128, n0 = blockIdx.x * 128;
  const int wm = (wave >> 1) * 64, wn = (wave & 1) * 64;
  f32x4 acc[4][4] = {};
  // staging map: wave w stages rows w*16..w*16+15 (and +64); lane covers 16B
  const int e0 = wave * 512 + lane * 8;
  const int row0 = e0 >> 5, kk0 = e0 & 31;   // row0 = wave*16 + lane/4, kk0 = (lane&3)*8
  const u16* pa = A  + (size_t)(m0 + row0) * K + kk0;
  const u16* pb = Bt + (size_t)(n0 + row0) * K + kk0;
  u16* la0 = &lA[wave * 512]; u16* la1 = &lA[2048 + wave * 512];
  u16* lb0 = &lB[wave * 512]; u16* lb1 = &lB[2048 + wave * 512];
  const size_t rstep = (size_t)64 * K;

  for (int kt = 0; kt < K; kt += 32){
    gload16(pa + kt,         la0);
    gload16(pa + rstep + kt, la1);
    gload16(pb + kt,         lb0);
    gload16(pb + rstep + kt, lb1);
    __syncthreads();                 // drains vmcnt -> LDS tile visible
    bf16x8 af[4], bfv[4];
    #pragma unroll
    for (int i = 0; i < 4; i++){
      af[i]  = __builtin_bit_cast(bf16x8, *(const u16x8*)&lA[(wm + i*16 + l16)*32 + quad*8]);
      bfv[i] = __builtin_bit_cast(bf16x8, *(const u16x8*)&lB[(wn + i*16 + l16)*32 + quad*8]);
    }
    #pragma unroll
    for (int i = 0; i < 4; i++)
      #pragma unroll
      for (int j = 0; j < 4; j++)
        acc[i][j] = __builtin_amdgcn_mfma_f32_16x16x32_bf16(af[i], bfv[j], acc[i][j], 0, 0, 0);
    __syncthreads();                 // all reads done before next DMA overwrites
  }
  // C/D layout: col = lane&15, row = quad*4 + reg
  #pragma unroll
  for (int i = 0; i < 4; i++){
    const int gr = m0 + wm + i*16 + quad*4;
    #pragma unroll
    for (int j = 0; j < 4; j++){
      const int gc = n0 + wn + j*16 + l16;
      float bv = 0.0f;
      if constexpr (EPI >= 1) bv = bias[gc];
      #pragma unroll
      for (int r = 0; r < 4; r++){
        float v = acc[i][j][r] + bv;
        if constexpr (EPI == 1) v = fmaxf(v, 0.0f);
        C[(size_t)(gr + r) * N + gc] = f2b(v);
      }
    }
  }
}

// ---------------- MFMA flash attention ----------------
// qkv: [NTOK][3*D] bf16 (q|k|v), ctx out: [NTOK][D] bf16
// grid (SEQ/64, BATCH*H), block 256. 64 q-rows/block; wave w owns q-rows w*16..+15.
__global__ __launch_bounds__(256) void attn_k(const u16* __restrict__ qkv,
    const int* __restrict__ tok, u16* __restrict__ ctx)
{
  constexpr int LDW = 72;   // padded row (u16): 144 B = 36 banks, 16B-aligned rows
  __shared__ __align__(16) u16 Qs[64*LDW];
  __shared__ __align__(16) u16 Ks[64*LDW];
  __shared__ __align__(16) u16 Vt[64*LDW];  // V transposed: [dk][key]
  __shared__ __align__(16) u16 Ps[64*LDW];  // P in A-frag layout, per-wave rows
  __shared__ float maskv[64];
  const int tid = threadIdx.x;
  const int wave = tid >> 6, lane = tid & 63;
  const int quad = lane >> 4, l16 = lane & 15;
  const int b = blockIdx.y >> 4, h = blockIdx.y & (H - 1);
  const int q0 = blockIdx.x * 64;
  const int skey = tid >> 2;            // staging row 0..63
  const int sdk  = (tid & 3) * 16;      // staging col {0,16,32,48}
  // ---- stage Q (scale 1/8 folded; exact power-of-2) ----
  {
    const u16* src = &qkv[((size_t)(b*SEQ + q0 + skey))*3072 + h*64 + sdk];
    u16x8 a = *(const u16x8*)src;
    u16x8 c = *(const u16x8*)(src + 8);
    u16x8 oa, oc;
    #pragma unroll
    for (int e = 0; e < 8; e++){ oa[e] = f2b(b2f(a[e])*0.125f); oc[e] = f2b(b2f(c[e])*0.125f); }
    *(u16x8*)&Qs[skey*LDW + sdk]     = oa;
    *(u16x8*)&Qs[skey*LDW + sdk + 8] = oc;
  }
  float m_r[4] = {-1e30f, -1e30f, -1e30f, -1e30f};
  float l_r[4] = {0.f, 0.f, 0.f, 0.f};
  f32x4 O[4] = {};                      // O[n]: row quad*4+r, col n*16+l16
  const int arow = (wave*16 + l16) * LDW;  // A-frag row base (Q and P)

  for (int kt = 0; kt < 16; ++kt){
    const int k0 = kt * 64;
    { // ---- stage K (row-major) and V (transposed) ----
      const u16* kr = &qkv[((size_t)(b*SEQ + k0 + skey))*3072 + h*64 + sdk];
      u16x8 k0v = *(const u16x8*)(kr + 1024);
      u16x8 k1v = *(const u16x8*)(kr + 1024 + 8);
      u16x8 v0v = *(const u16x8*)(kr + 2048);
      u16x8 v1v = *(const u16x8*)(kr + 2048 + 8);
      *(u16x8*)&Ks[skey*LDW + sdk]     = k0v;
      *(u16x8*)&Ks[skey*LDW + sdk + 8] = k1v;
      #pragma unroll
      for (int e = 0; e < 8; e++){
        Vt[(sdk + e)*LDW + skey]     = v0v[e];
        Vt[(sdk + 8 + e)*LDW + skey] = v1v[e];
      }
      if (tid < 64) maskv[tid] = (tok[b*SEQ + k0 + tid] != 0) ? 0.0f : -1.0e9f;
    }
    __syncthreads();
    // ---- QK^T: wave's 16 q-rows x 64 keys ----
    bf16x8 qf0 = __builtin_bit_cast(bf16x8, *(const u16x8*)&Qs[arow + quad*8]);
    bf16x8 qf1 = __builtin_bit_cast(bf16x8, *(const u16x8*)&Qs[arow + 32 + quad*8]);
    f32x4 s[4];
    #pragma unroll
    for (int j = 0; j < 4; j++){
      bf16x8 kf0 = __builtin_bit_cast(bf16x8, *(const u16x8*)&Ks[(j*16 + l16)*LDW + quad*8]);
      bf16x8 kf1 = __builtin_bit_cast(bf16x8, *(const u16x8*)&Ks[(j*16 + l16)*LDW + 32 + quad*8]);
      f32x4 z = {};
      z = __builtin_amdgcn_mfma_f32_16x16x32_bf16(qf0, kf0, z, 0, 0, 0);
      z = __builtin_amdgcn_mfma_f32_16x16x32_bf16(qf1, kf1, z, 0, 0, 0);
      s[j] = z;
    }
    // ---- online softmax (rows quad*4+r, cols j*16+l16) ----
    float mvj[4];
    #pragma unroll
    for (int j = 0; j < 4; j++) mvj[j] = maskv[j*16 + l16];
    float rmax[4];
    #pragma unroll
    for (int r = 0; r < 4; r++){
      float a = s[0][r] + mvj[0];
      a = fmaxf(a, s[1][r] + mvj[1]);
      a = fmaxf(a, s[2][r] + mvj[2]);
      a = fmaxf(a, s[3][r] + mvj[3]);
      rmax[r] = a;
    }
    #pragma unroll
    for (int o = 1; o < 16; o <<= 1){
      #pragma unroll
      for (int r = 0; r < 4; r++) rmax[r] = fmaxf(rmax[r], __shfl_xor(rmax[r], o, 64));
    }
    float al[4], rsum[4];
    #pragma unroll
    for (int r = 0; r < 4; r++){
      float mn = fmaxf(m_r[r], rmax[r]);
      al[r] = __expf(m_r[r] - mn);
      m_r[r] = mn;
      rsum[r] = 0.0f;
    }
    #pragma unroll
    for (int j = 0; j < 4; j++){
      #pragma unroll
      for (int r = 0; r < 4; r++){
        float p = __expf(s[j][r] + mvj[j] - m_r[r]);
        rsum[r] += p;
        Ps[(wave*16 + quad*4 + r)*LDW + j*16 + l16] = f2b(p);   // per-wave region
      }
    }
    #pragma unroll
    for (int o = 1; o < 16; o <<= 1){
      #pragma unroll
      for (int r = 0; r < 4; r++) rsum[r] += __shfl_xor(rsum[r], o, 64);
    }
    #pragma unroll
    for (int r = 0; r < 4; r++) l_r[r] = l_r[r]*al[r] + rsum[r];
    #pragma unroll
    for (int n = 0; n < 4; n++)
      #pragma unroll
      for (int r = 0; r < 4; r++) O[n][r] *= al[r];
    // ---- PV: P (A-frag, own wave rows) x V^T (B-frag) ----
    bf16x8 pf0 = __builtin_bit_cast(bf16x8, *(const u16x8*)&Ps[arow + quad*8]);
    bf16x8 pf1 = __builtin_bit_cast(bf16x8, *(const u16x8*)&Ps[arow + 32 + quad*8]);
    #pragma unroll
    for (int n = 0; n < 4; n++){
      bf16x8 vf0 = __builtin_bit_cast(bf16x8, *(const u16x8*)&Vt[(n*16 + l16)*LDW + quad*8]);
      bf16x8 vf1 = __builtin_bit_cast(bf16x8, *(const u16x8*)&Vt[(n*16 + l16)*LDW + 32 + quad*8]);
      O[n] = __builtin_amdgcn_mfma_f32_16x16x32_bf16(pf0, vf0, O[n], 0, 0, 0);
      O[n] = __builtin_amdgcn_mfma_f32_16x16x32_bf16(pf1, vf1, O[n], 0, 0, 0);
    }
    __syncthreads();   // K/Vt fully consumed before next tile staging
  }
  // ---- output ----
  #pragma unroll
  for (int r = 0; r < 4; r++){
    float inv = 1.0f / l_r[r];
    size_t ro = ((size_t)(b*SEQ + q0 + wave*16 + quad*4 + r))*D + h*64;
    #pragma unroll
    for (int n = 0; n < 4; n++)
      ctx[ro + n*16 + l16] = f2b(O[n][r] * inv);
  }
}

// ---------------- host ----------------
extern "C" void kernel_launch(void* const* d_in, const int* in_sizes, int n_in,
                              void* d_out, int out_size, void* d_ws, size_t ws_size,
                              hipStream_t stream)
{
  (void)in_sizes; (void)n_in; (void)out_size; (void)ws_size;
  const int*   tok = (const int*)d_in[0];
  const float* emb = (const float*)d_in[1];
  const float* Wq  = (const float*)d_in[2];
  const float* Wk  = (const float*)d_in[3];
  const float* Wv  = (const float*)d_in[4];
  const float* Wo  = (const float*)d_in[5];
  const float* W1  = (const float*)d_in[6];
  const float* b1  = (const float*)d_in[7];
  const float* W2  = (const float*)d_in[8];
  const float* b2  = (const float*)d_in[9];
  const float* ln1w = (const float*)d_in[10];
  const float* ln1b = (const float*)d_in[11];
  const float* ln2w = (const float*)d_in[12];
  const float* ln2b = (const float*)d_in[13];
  const float* fnw  = (const float*)d_in[14];
  const float* fnb  = (const float*)d_in[15];
  float* out = (float*)d_out;

  // workspace layout (144 MB total):
  char* wp = (char*)d_ws;
  float* x  = (float*)wp;                              // fp32 residual, 32 MB
  u16* xb   = (u16*)(wp + (size_t)32*1024*1024);       // bf16 residual, 16 MB
  u16* big  = (u16*)(wp + (size_t)48*1024*1024);       // qkv (48 MB) / h1 chunk (32 MB)
  u16* ctx  = (u16*)(wp + (size_t)96*1024*1024);       // 16 MB
  u16* tmp  = (u16*)(wp + (size_t)112*1024*1024);      // bf16 delta, 16 MB
  u16* wtmp = (u16*)(wp + (size_t)128*1024*1024);      // transposed bf16 weights, 16 MB

  embed_k<<<NTOK, 256, 0, stream>>>(tok, emb, x, xb);

  for (int l = 0; l < L; ++l){
    transpose_k<<<dim3(D/32, D/32), 256, 0, stream>>>(Wq + (size_t)l*D*D, wtmp, D, D);
    transpose_k<<<dim3(D/32, D/32), 256, 0, stream>>>(Wk + (size_t)l*D*D, wtmp + (size_t)D*D, D, D);
    transpose_k<<<dim3(D/32, D/32), 256, 0, stream>>>(Wv + (size_t)l*D*D, wtmp + (size_t)2*D*D, D, D);
    gemm_bt<0><<<dim3(3*D/128, NTOK/128), 256, 0, stream>>>(xb, wtmp, big, nullptr, NTOK, 3*D, D);
    attn_k<<<dim3(SEQ/64, BATCH*H), 256, 0, stream>>>(big, tok, ctx);
    transpose_k<<<dim3(D/32, D/32), 256, 0, stream>>>(Wo + (size_t)l*D*D, wtmp, D, D);
    gemm_bt<0><<<dim3(D/128, NTOK/128), 256, 0, stream>>>(ctx, wtmp, tmp, nullptr, NTOK, D, D);
    ln_k<<<NTOK, 256, 0, stream>>>(x, tmp, ln1w + (size_t)l*D, ln1b + (size_t)l*D, x, xb, 1e-6f);
    transpose_k<<<dim3(FF/32, D/32), 256, 0, stream>>>(W1 + (size_t)l*D*FF, wtmp, D, FF);
    transpose_k<<<dim3(D/32, FF/32), 256, 0, stream>>>(W2 + (size_t)l*FF*D, wtmp + (size_t)D*FF, FF, D);
    for (int mc = 0; mc < 2; ++mc){
      const u16* ain = xb + (size_t)mc*4096*D;
      u16* cout = tmp + (size_t)mc*4096*D;
      gemm_bt<1><<<dim3(FF/128, 4096/128), 256, 0, stream>>>(ain, wtmp, big, b1 + (size_t)l*FF, 4096, FF, D);
      gemm_bt<2><<<dim3(D/128, 4096/128), 256, 0, stream>>>(big, wtmp + (size_t)D*FF, cout, b2 + (size_t)l*D, 4096, D, FF);
    }
    ln_k<<<NTOK, 256, 0, stream>>>(x, tmp, ln2w + (size_t)l*D, ln2b + (size_t)l*D, x, xb, 1e-6f);
  }
  ln_k<<<NTOK, 256, 0, stream>>>(x, nullptr, fnw, fnb, out, nullptr, 1e-5f);
}

// Round 5
// 3634.948 us; speedup vs baseline: 1.7430x; 1.0372x over previous
//
#include <hip/hip_runtime.h>
#include <cstdint>
#include <cstddef>

typedef unsigned short u16;
typedef __bf16 bf16x8 __attribute__((ext_vector_type(8)));
typedef float f32x4 __attribute__((ext_vector_type(4)));
typedef unsigned short u16x8 __attribute__((ext_vector_type(8)));
typedef unsigned short u16x4 __attribute__((ext_vector_type(4)));
typedef __attribute__((address_space(1))) void* gas_ptr;
typedef __attribute__((address_space(3))) void* las_ptr;

static constexpr int D = 1024, FF = 4096, L = 6, H = 16, SEQ = 1024, BATCH = 8;
static constexpr int NTOK = BATCH * SEQ; // 8192

__device__ __forceinline__ float b2f(u16 u){ unsigned int i = ((unsigned int)u) << 16; return __builtin_bit_cast(float, i); }
__device__ __forceinline__ u16 f2b(float f){
  unsigned int i = __builtin_bit_cast(unsigned int, f);
  i += 0x7FFFu + ((i >> 16) & 1u);           // round-to-nearest-even
  return (u16)(i >> 16);
}
__device__ __forceinline__ void gload16(const void* g, void* l){
  // async global->LDS DMA, 16B/lane; LDS dest = wave-uniform base + lane*16
  __builtin_amdgcn_global_load_lds((gas_ptr)g, (las_ptr)l, 16, 0, 0);
}

// ---------------- embedding + positional encoding ----------------
__global__ __launch_bounds__(256) void embed_k(const int* __restrict__ tok,
    const float* __restrict__ emb, float* __restrict__ x, u16* __restrict__ xb)
{
  int idx = blockIdx.x * 256 + threadIdx.x;   // one thread per 4 elements
  int row = idx >> 8;
  int g = idx & 255;
  int t = tok[row];
  int s = row & (SEQ - 1);
  int d0 = g * 4;
  const float c = -logf(10000.0f) / (float)D;
  float a0 = (float)s * expf((float)d0 * c);
  float a1 = (float)s * expf((float)(d0 + 2) * c);
  float4 e = *(const float4*)&emb[(size_t)t * D + d0];
  float v0 = e.x * 32.0f + sinf(a0);
  float v1 = e.y * 32.0f + cosf(a0);
  float v2 = e.z * 32.0f + sinf(a1);
  float v3 = e.w * 32.0f + cosf(a1);
  size_t o = (size_t)row * D + d0;
  *(float4*)&x[o] = make_float4(v0, v1, v2, v3);
  u16x4 bb = { f2b(v0), f2b(v1), f2b(v2), f2b(v3) };
  *(u16x4*)&xb[o] = bb;
}

// ---------------- fused residual + LayerNorm ----------------
__global__ __launch_bounds__(256) void ln_k(const float* __restrict__ xin,
    const u16* __restrict__ delta, const float* __restrict__ w, const float* __restrict__ bi,
    float* __restrict__ xout, u16* __restrict__ bout, float eps)
{
  int row = blockIdx.x, tid = threadIdx.x;
  int wave = tid >> 6, lane = tid & 63;
  size_t base = (size_t)row * D;
  int c0 = tid * 4;
  float4 v = *(const float4*)&xin[base + c0];
  if (delta){
    u16x4 dd = *(const u16x4*)&delta[base + c0];
    v.x += b2f(dd[0]); v.y += b2f(dd[1]); v.z += b2f(dd[2]); v.w += b2f(dd[3]);
  }
  float s = v.x + v.y + v.z + v.w;
  #pragma unroll
  for (int o = 32; o >= 1; o >>= 1) s += __shfl_down(s, o, 64);
  __shared__ float red[4];
  if (lane == 0) red[wave] = s;
  __syncthreads();
  float mean = (red[0] + red[1] + red[2] + red[3]) * (1.0f / D);
  __syncthreads();
  float d0 = v.x - mean, d1 = v.y - mean, d2 = v.z - mean, d3 = v.w - mean;
  float s2 = d0*d0 + d1*d1 + d2*d2 + d3*d3;
  #pragma unroll
  for (int o = 32; o >= 1; o >>= 1) s2 += __shfl_down(s2, o, 64);
  if (lane == 0) red[wave] = s2;
  __syncthreads();
  float var = (red[0] + red[1] + red[2] + red[3]) * (1.0f / D);
  float inv = rsqrtf(var + eps);
  float4 wv = *(const float4*)&w[c0];
  float4 bv = *(const float4*)&bi[c0];
  float o0 = d0 * inv * wv.x + bv.x;
  float o1 = d1 * inv * wv.y + bv.y;
  float o2 = d2 * inv * wv.z + bv.z;
  float o3 = d3 * inv * wv.w + bv.w;
  if (xout) *(float4*)&xout[base + c0] = make_float4(o0, o1, o2, o3);
  if (bout){
    u16x4 ob = { f2b(o0), f2b(o1), f2b(o2), f2b(o3) };
    *(u16x4*)&bout[base + c0] = ob;
  }
}

// ---------------- fp32 -> bf16 transpose (weights -> B^T form) ----------------
__global__ __launch_bounds__(256) void transpose_k(const float* __restrict__ in,
    u16* __restrict__ out, int R, int C)
{
  __shared__ __align__(16) u16 t[32][33];
  int bx = blockIdx.x, by = blockIdx.y;
  int x = threadIdx.x & 31, y = threadIdx.x >> 5;
  #pragma unroll
  for (int r = 0; r < 4; r++){
    int row = by * 32 + y + r * 8;
    t[y + r * 8][x] = f2b(in[(size_t)row * C + bx * 32 + x]);
  }
  __syncthreads();
  #pragma unroll
  for (int r = 0; r < 4; r++){
    int orow = bx * 32 + y + r * 8;
    out[(size_t)orow * R + by * 32 + x] = t[x][y + r * 8];
  }
}

// ---- batched DxD transpose of Wq|Wk|Wv|Wo; z selects source; Wq scaled ----
struct Ptr4 { const float *a, *b, *c, *d; };
__global__ __launch_bounds__(256) void transpose4_k(Ptr4 srcs, u16* __restrict__ out, float s0)
{
  int z = blockIdx.z;
  const float* in = (z == 0) ? srcs.a : (z == 1) ? srcs.b : (z == 2) ? srcs.c : srcs.d;
  float sc = (z == 0) ? s0 : 1.0f;
  u16* o = out + (size_t)z * D * D;
  __shared__ __align__(16) u16 t[32][33];
  int bx = blockIdx.x, by = blockIdx.y;
  int x = threadIdx.x & 31, y = threadIdx.x >> 5;
  #pragma unroll
  for (int r = 0; r < 4; r++){
    int row = by * 32 + y + r * 8;
    t[y + r * 8][x] = f2b(in[(size_t)row * D + bx * 32 + x] * sc);
  }
  __syncthreads();
  #pragma unroll
  for (int r = 0; r < 4; r++){
    int orow = bx * 32 + y + r * 8;
    o[(size_t)orow * D + by * 32 + x] = t[x][y + r * 8];
  }
}

// ---- V transpose: qkv [tok][2048 + h*64 + dk] -> vt [(b*16+h)*64 + dk][s] ----
__global__ __launch_bounds__(256) void vtrans_k(const u16* __restrict__ qkv, u16* __restrict__ vt)
{
  __shared__ __align__(16) u16 t[32][34];
  int bx = blockIdx.x;      // s tile 0..31
  int by = blockIdx.y;      // dk tile 0..1
  int bh = blockIdx.z;      // b*16+h
  int b = bh >> 4, h = bh & 15;
  int x = threadIdx.x & 31, y = threadIdx.x >> 5;
  #pragma unroll
  for (int r = 0; r < 4; r++){
    int s = bx * 32 + y + r * 8;
    t[y + r * 8][x] = qkv[((size_t)(b * SEQ + s)) * 3072 + 2048 + h * 64 + by * 32 + x];
  }
  __syncthreads();
  #pragma unroll
  for (int r = 0; r < 4; r++){
    int dk = by * 32 + y + r * 8;
    vt[((size_t)bh * 64 + dk) * SEQ + bx * 32 + x] = t[x][y + r * 8];
  }
}

// ---------------- bf16 MFMA GEMM (m97 structure: global_load_lds w=16) ----------
// A: [M][K] bf16, Bt: [N][K] bf16. 128x128 tile, BK=32, 4 waves (2x2 of 64x64).
// EPI: 0 = plain bf16 out, 1 = bias+relu bf16 out, 2 = bias bf16 out
template<int EPI>
__global__ __launch_bounds__(256) void gemm_bt(const u16* __restrict__ A,
    const u16* __restrict__ Bt, u16* __restrict__ C, const float* __restrict__ bias,
    int M, int N, int K)
{
  __shared__ __align__(16) u16 lA[4096];  // [128 rows][32 k]
  __shared__ __align__(16) u16 lB[4096];
  const int tid = threadIdx.x;
  const int wave = tid >> 6, lane = tid & 63;
  const int quad = lane >> 4, l16 = lane & 15;
  const int m0 = blockIdx.y * 128, n0 = blockIdx.x * 128;
  const int wm = (wave >> 1) * 64, wn = (wave & 1) * 64;
  f32x4 acc[4][4] = {};
  const int e0 = wave * 512 + lane * 8;
  const int row0 = e0 >> 5, kk0 = e0 & 31;
  const u16* pa = A  + (size_t)(m0 + row0) * K + kk0;
  const u16* pb = Bt + (size_t)(n0 + row0) * K + kk0;
  u16* la0 = &lA[wave * 512]; u16* la1 = &lA[2048 + wave * 512];
  u16* lb0 = &lB[wave * 512]; u16* lb1 = &lB[2048 + wave * 512];
  const size_t rstep = (size_t)64 * K;

  for (int kt = 0; kt < K; kt += 32){
    gload16(pa + kt,         la0);
    gload16(pa + rstep + kt, la1);
    gload16(pb + kt,         lb0);
    gload16(pb + rstep + kt, lb1);
    __syncthreads();                 // drains vmcnt -> LDS tile visible
    bf16x8 af[4], bfv[4];
    #pragma unroll
    for (int i = 0; i < 4; i++){
      af[i]  = __builtin_bit_cast(bf16x8, *(const u16x8*)&lA[(wm + i*16 + l16)*32 + quad*8]);
      bfv[i] = __builtin_bit_cast(bf16x8, *(const u16x8*)&lB[(wn + i*16 + l16)*32 + quad*8]);
    }
    #pragma unroll
    for (int i = 0; i < 4; i++)
      #pragma unroll
      for (int j = 0; j < 4; j++)
        acc[i][j] = __builtin_amdgcn_mfma_f32_16x16x32_bf16(af[i], bfv[j], acc[i][j], 0, 0, 0);
    __syncthreads();                 // all reads done before next DMA overwrites
  }
  // C/D layout: col = lane&15, row = quad*4 + reg
  #pragma unroll
  for (int i = 0; i < 4; i++){
    const int gr = m0 + wm + i*16 + quad*4;
    #pragma unroll
    for (int j = 0; j < 4; j++){
      const int gc = n0 + wn + j*16 + l16;
      float bv = 0.0f;
      if constexpr (EPI >= 1) bv = bias[gc];
      #pragma unroll
      for (int r = 0; r < 4; r++){
        float v = acc[i][j][r] + bv;
        if constexpr (EPI == 1) v = fmaxf(v, 0.0f);
        C[(size_t)(gr + r) * N + gc] = f2b(v);
      }
    }
  }
}

// ---------------- MFMA flash attention ----------------
// qkv: [NTOK][3*D] bf16 (q|k|v; q pre-scaled by 1/8 via Wq), vt: [b*16+h][64][SEQ]
// grid (SEQ/64, BATCH*H), block 256. Wave w owns q-rows w*16..+15.
__global__ __launch_bounds__(256) void attn_k(const u16* __restrict__ qkv,
    const u16* __restrict__ vt, const int* __restrict__ tok, u16* __restrict__ ctx)
{
  constexpr int LDW = 72;   // padded row (u16): 144 B, 16B-aligned rows
  __shared__ __align__(16) u16 QPs[64*LDW];  // Q, then reused as P (per-wave rows)
  __shared__ __align__(16) u16 Ks[64*LDW];
  __shared__ __align__(16) u16 Vt[64*LDW];   // [dk][key]
  __shared__ float maskv[64];
  const int tid = threadIdx.x;
  const int wave = tid >> 6, lane = tid & 63;
  const int quad = lane >> 4, l16 = lane & 15;
  const int bh = blockIdx.y;
  const int b = bh >> 4, h = bh & (H - 1);
  const int q0 = blockIdx.x * 64;
  const int skey = tid >> 2;            // staging row 0..63
  const int sdk  = (tid & 3) * 16;      // staging col {0,16,32,48}
  // ---- stage Q (already scaled) ----
  {
    const u16* src = &qkv[((size_t)(b*SEQ + q0 + skey))*3072 + h*64 + sdk];
    *(u16x8*)&QPs[skey*LDW + sdk]     = *(const u16x8*)src;
    *(u16x8*)&QPs[skey*LDW + sdk + 8] = *(const u16x8*)(src + 8);
  }
  __syncthreads();
  const int arow = (wave*16 + l16) * LDW;  // A-frag row base (Q and P)
  bf16x8 qf0 = __builtin_bit_cast(bf16x8, *(const u16x8*)&QPs[arow + quad*8]);
  bf16x8 qf1 = __builtin_bit_cast(bf16x8, *(const u16x8*)&QPs[arow + 32 + quad*8]);
  float m_r[4] = {-1e30f, -1e30f, -1e30f, -1e30f};
  float l_r[4] = {0.f, 0.f, 0.f, 0.f};
  f32x4 O[4] = {};                      // O[n]: row quad*4+r, col n*16+l16

  for (int kt = 0; kt < 16; ++kt){
    const int k0 = kt * 64;
    { // ---- stage K rows and V^T rows (both contiguous vector copies) ----
      const u16* kr = &qkv[((size_t)(b*SEQ + k0 + skey))*3072 + 1024 + h*64 + sdk];
      const u16* vr = &vt[((size_t)bh*64 + skey)*SEQ + k0 + sdk];
      u16x8 k0v = *(const u16x8*)kr;
      u16x8 k1v = *(const u16x8*)(kr + 8);
      u16x8 v0v = *(const u16x8*)vr;
      u16x8 v1v = *(const u16x8*)(vr + 8);
      *(u16x8*)&Ks[skey*LDW + sdk]     = k0v;
      *(u16x8*)&Ks[skey*LDW + sdk + 8] = k1v;
      *(u16x8*)&Vt[skey*LDW + sdk]     = v0v;
      *(u16x8*)&Vt[skey*LDW + sdk + 8] = v1v;
      if (tid < 64) maskv[tid] = (tok[b*SEQ + k0 + tid] != 0) ? 0.0f : -1.0e9f;
    }
    __syncthreads();
    // ---- QK^T: wave's 16 q-rows x 64 keys ----
    f32x4 s[4];
    #pragma unroll
    for (int j = 0; j < 4; j++){
      bf16x8 kf0 = __builtin_bit_cast(bf16x8, *(const u16x8*)&Ks[(j*16 + l16)*LDW + quad*8]);
      bf16x8 kf1 = __builtin_bit_cast(bf16x8, *(const u16x8*)&Ks[(j*16 + l16)*LDW + 32 + quad*8]);
      f32x4 z = {};
      z = __builtin_amdgcn_mfma_f32_16x16x32_bf16(qf0, kf0, z, 0, 0, 0);
      z = __builtin_amdgcn_mfma_f32_16x16x32_bf16(qf1, kf1, z, 0, 0, 0);
      s[j] = z;
    }
    // ---- online softmax (rows quad*4+r, cols j*16+l16) ----
    float mvj[4];
    #pragma unroll
    for (int j = 0; j < 4; j++) mvj[j] = maskv[j*16 + l16];
    float rmax[4];
    #pragma unroll
    for (int r = 0; r < 4; r++){
      float a = s[0][r] + mvj[0];
      a = fmaxf(a, s[1][r] + mvj[1]);
      a = fmaxf(a, s[2][r] + mvj[2]);
      a = fmaxf(a, s[3][r] + mvj[3]);
      rmax[r] = a;
    }
    #pragma unroll
    for (int o = 1; o < 16; o <<= 1){
      #pragma unroll
      for (int r = 0; r < 4; r++) rmax[r] = fmaxf(rmax[r], __shfl_xor(rmax[r], o, 64));
    }
    float al[4], rsum[4];
    #pragma unroll
    for (int r = 0; r < 4; r++){
      float mn = fmaxf(m_r[r], rmax[r]);
      al[r] = __expf(m_r[r] - mn);
      m_r[r] = mn;
      rsum[r] = 0.0f;
    }
    #pragma unroll
    for (int j = 0; j < 4; j++){
      #pragma unroll
      for (int r = 0; r < 4; r++){
        float p = __expf(s[j][r] + mvj[j] - m_r[r]);
        rsum[r] += p;
        QPs[(wave*16 + quad*4 + r)*LDW + j*16 + l16] = f2b(p);  // own-wave rows
      }
    }
    #pragma unroll
    for (int o = 1; o < 16; o <<= 1){
      #pragma unroll
      for (int r = 0; r < 4; r++) rsum[r] += __shfl_xor(rsum[r], o, 64);
    }
    #pragma unroll
    for (int r = 0; r < 4; r++) l_r[r] = l_r[r]*al[r] + rsum[r];
    #pragma unroll
    for (int n = 0; n < 4; n++)
      #pragma unroll
      for (int r = 0; r < 4; r++) O[n][r] *= al[r];
    // ---- PV: P (A-frag, own wave rows) x V^T (B-frag) ----
    bf16x8 pf0 = __builtin_bit_cast(bf16x8, *(const u16x8*)&QPs[arow + quad*8]);
    bf16x8 pf1 = __builtin_bit_cast(bf16x8, *(const u16x8*)&QPs[arow + 32 + quad*8]);
    #pragma unroll
    for (int n = 0; n < 4; n++){
      bf16x8 vf0 = __builtin_bit_cast(bf16x8, *(const u16x8*)&Vt[(n*16 + l16)*LDW + quad*8]);
      bf16x8 vf1 = __builtin_bit_cast(bf16x8, *(const u16x8*)&Vt[(n*16 + l16)*LDW + 32 + quad*8]);
      O[n] = __builtin_amdgcn_mfma_f32_16x16x32_bf16(pf0, vf0, O[n], 0, 0, 0);
      O[n] = __builtin_amdgcn_mfma_f32_16x16x32_bf16(pf1, vf1, O[n], 0, 0, 0);
    }
    __syncthreads();   // Ks/Vt fully consumed before next tile staging
  }
  // ---- output ----
  #pragma unroll
  for (int r = 0; r < 4; r++){
    float inv = 1.0f / l_r[r];
    size_t ro = ((size_t)(b*SEQ + q0 + wave*16 + quad*4 + r))*D + h*64;
    #pragma unroll
    for (int n = 0; n < 4; n++)
      ctx[ro + n*16 + l16] = f2b(O[n][r] * inv);
  }
}

// ---------------- host ----------------
extern "C" void kernel_launch(void* const* d_in, const int* in_sizes, int n_in,
                              void* d_out, int out_size, void* d_ws, size_t ws_size,
                              hipStream_t stream)
{
  (void)in_sizes; (void)n_in; (void)out_size; (void)ws_size;
  const int*   tok = (const int*)d_in[0];
  const float* emb = (const float*)d_in[1];
  const float* Wq  = (const float*)d_in[2];
  const float* Wk  = (const float*)d_in[3];
  const float* Wv  = (const float*)d_in[4];
  const float* Wo  = (const float*)d_in[5];
  const float* W1  = (const float*)d_in[6];
  const float* b1  = (const float*)d_in[7];
  const float* W2  = (const float*)d_in[8];
  const float* b2  = (const float*)d_in[9];
  const float* ln1w = (const float*)d_in[10];
  const float* ln1b = (const float*)d_in[11];
  const float* ln2w = (const float*)d_in[12];
  const float* ln2b = (const float*)d_in[13];
  const float* fnw  = (const float*)d_in[14];
  const float* fnb  = (const float*)d_in[15];
  float* out = (float*)d_out;

  // workspace layout (144 MB total):
  char* wp = (char*)d_ws;
  float* x  = (float*)wp;                              // fp32 residual, 32 MB
  u16* xb   = (u16*)(wp + (size_t)32*1024*1024);       // bf16 residual, 16 MB
  u16* big  = (u16*)(wp + (size_t)48*1024*1024);       // qkv (48 MB) / h1 chunk (32 MB)
  u16* ctx  = (u16*)(wp + (size_t)96*1024*1024);       // 16 MB
  u16* tmp  = (u16*)(wp + (size_t)112*1024*1024);      // vT during attn, then bf16 delta (16 MB)
  u16* wtmp = (u16*)(wp + (size_t)128*1024*1024);      // transposed bf16 weights, 16 MB

  embed_k<<<NTOK, 256, 0, stream>>>(tok, emb, x, xb);

  for (int l = 0; l < L; ++l){
    // Wq^T|Wk^T|Wv^T|Wo^T batched (Wq scaled by 1/8 for attention)
    Ptr4 qp{ Wq + (size_t)l*D*D, Wk + (size_t)l*D*D, Wv + (size_t)l*D*D, Wo + (size_t)l*D*D };
    transpose4_k<<<dim3(D/32, D/32, 4), 256, 0, stream>>>(qp, wtmp, 0.125f);
    gemm_bt<0><<<dim3(3*D/128, NTOK/128), 256, 0, stream>>>(xb, wtmp, big, nullptr, NTOK, 3*D, D);
    vtrans_k<<<dim3(SEQ/32, 2, BATCH*H), 256, 0, stream>>>(big, tmp);
    attn_k<<<dim3(SEQ/64, BATCH*H), 256, 0, stream>>>(big, tmp, tok, ctx);
    gemm_bt<0><<<dim3(D/128, NTOK/128), 256, 0, stream>>>(ctx, wtmp + (size_t)3*D*D, tmp, nullptr, NTOK, D, D);
    ln_k<<<NTOK, 256, 0, stream>>>(x, tmp, ln1w + (size_t)l*D, ln1b + (size_t)l*D, x, xb, 1e-6f);
    // FFN
    transpose_k<<<dim3(FF/32, D/32), 256, 0, stream>>>(W1 + (size_t)l*D*FF, wtmp, D, FF);
    transpose_k<<<dim3(D/32, FF/32), 256, 0, stream>>>(W2 + (size_t)l*FF*D, wtmp + (size_t)D*FF, FF, D);
    for (int mc = 0; mc < 2; ++mc){
      const u16* ain = xb + (size_t)mc*4096*D;
      u16* cout = tmp + (size_t)mc*4096*D;
      gemm_bt<1><<<dim3(FF/128, 4096/128), 256, 0, stream>>>(ain, wtmp, big, b1 + (size_t)l*FF, 4096, FF, D);
      gemm_bt<2><<<dim3(D/128, 4096/128), 256, 0, stream>>>(big, wtmp + (size_t)D*FF, cout, b2 + (size_t)l*D, 4096, D, FF);
    }
    ln_k<<<NTOK, 256, 0, stream>>>(x, tmp, ln2w + (size_t)l*D, ln2b + (size_t)l*D, x, xb, 1e-6f);
  }
  ln_k<<<NTOK, 256, 0, stream>>>(x, nullptr, fnw, fnb, out, nullptr, 1e-5f);
}